// Round 5
// baseline (503.264 us; speedup 1.0000x reference)
//
#include <hip/hip_runtime.h>
#include <cmath>
#include <cstdint>

#define NROWS 65536
#define DIMN  256
#define NRF   256
#define OUTD  1024
#define KDIM  1024   // 4*NRF
#define MCOEF 0.001f

typedef __bf16 v8bf __attribute__((ext_vector_type(8)));
typedef float  v4f  __attribute__((ext_vector_type(4)));
typedef float  f32x16 __attribute__((ext_vector_type(16)));
typedef unsigned short us8 __attribute__((ext_vector_type(8)));

__device__ __forceinline__ unsigned short f2bf(float f) {
  unsigned int u = __float_as_uint(f);
  u += 0x7fffu + ((u >> 16) & 1u);   // round-to-nearest-even
  return (unsigned short)(u >> 16);
}

__device__ __forceinline__ void async_copy16(const void* g, void* l) {
  __builtin_amdgcn_global_load_lds(
      (const __attribute__((address_space(1))) void*)g,
      (__attribute__((address_space(3))) void*)l, 16, 0, 0);
}

// XOR-swizzled tile layout for the feature kernel (32-wide K tiles).
__device__ __forceinline__ int sw_slot(int r, int c) {
  return r * 4 + ((c ^ (r >> 1)) & 3);
}

// proj -> bf16, and mg2[i] = M * ||proj_i||^2 (fp32)
__global__ __launch_bounds__(64) void prep_rf(
    const float* __restrict__ proj, unsigned short* __restrict__ projbf,
    float* __restrict__ mg2) {
  int i = blockIdx.x;
  int lane = threadIdx.x;  // 64 threads
  float4 v = ((const float4*)(proj + (size_t)i * DIMN))[lane];
  ushort4 o;
  o.x = f2bf(v.x); o.y = f2bf(v.y); o.z = f2bf(v.z); o.w = f2bf(v.w);
  ((ushort4*)(projbf + (size_t)i * DIMN))[lane] = o;
  float ss = v.x * v.x + v.y * v.y + v.z * v.z + v.w * v.w;
#pragma unroll
  for (int off = 32; off > 0; off >>= 1) ss += __shfl_down(ss, off, 64);
  if (lane == 0) mg2[i] = MCOEF * ss;
}

// Fused feature kernel for BOTH x (blocks 16..1039) and weights (blocks 0..15).
// K layout INTERLEAVED: column k = 4*rf + component (identical F and Wp).
// 2-phase prefetch K-loop + direct ushort4 epilogue stores.
__global__ __launch_bounds__(256) void fused_features(
    const float* __restrict__ srcX,          // 65536 x 256 fp32
    const float* __restrict__ srcW,          // 1024 x 256 fp32
    const float* __restrict__ biasW,         // raw b (scaled by 0.25 here)
    const float* __restrict__ xr_g, const float* __restrict__ xi_g,
    const float* __restrict__ mg2_g,
    const unsigned short* __restrict__ projbf,  // 256 x 256 bf16
    unsigned short* __restrict__ FX,         // 65536 x 1024 bf16
    unsigned short* __restrict__ FW,         // 1024 x 1024 bf16
    float sRx, float sRw, float scaleC) {
  __shared__ __align__(16) unsigned short As[2][64 * 32];    // 2 x 4 KB
  __shared__ __align__(16) unsigned short Bs[2][256 * 32];   // 2 x 16 KB
  __shared__ float xr_s[256], xi_s[256], c1_s[256], c2_s[256], mg2_s[256];
  __shared__ float sq_s[64], bias_s[64];

  int t = threadIdx.x;
  int lane = t & 63;
  int w = t >> 6;

  bool isW = blockIdx.x < (OUTD / 64);
  int blockRow = isW ? blockIdx.x * 64 : (blockIdx.x - OUTD / 64) * 64;
  const float* src = isW ? srcW : srcX;
  float scl = isW ? 0.25f : (1.f / DIMN);
  unsigned short* Fout = isW ? FW : FX;
  float sR = isW ? sRw : sRx;
  float sI = isW ? -sRw : sRx;

  {
    float a = xr_g[t], b = xi_g[t];
    xr_s[t] = a; xi_s[t] = b;
    c1_s[t] = a * a - b * b;   // Re(z^2)
    c2_s[t] = 2.f * a * b;     // Im(z^2)
    mg2_s[t] = mg2_g[t];
  }
  if (t < 64) bias_s[t] = isW ? biasW[blockRow + t] * 0.25f : 0.f;

  v4f acc[4][4];
#pragma unroll
  for (int a = 0; a < 4; a++)
#pragma unroll
    for (int b = 0; b < 4; b++)
#pragma unroll
      for (int q = 0; q < 4; q++) acc[a][b][q] = 0.f;

  int arow = t >> 2, sub = t & 3;
  const float* srow = src + (size_t)(blockRow + arow) * DIMN + sub * 8;
  float ss = 0.f;

  auto stageB = [&](int nb, int kb) {
#pragma unroll
    for (int r = 0; r < 4; r++) {
      int idx = r * 256 + t;
      int row = idx >> 2, kc = ((idx & 3) ^ ((idx >> 3) & 3)) * 8;
      async_copy16(projbf + (size_t)row * DIMN + kb + kc,
                   &Bs[nb][(idx & ~63) * 8]);
    }
  };
  auto stageA = [&](int nb, int kb) {
    float4 v0 = *(const float4*)(srow + kb);
    float4 v1 = *(const float4*)(srow + kb + 4);
    v0.x *= scl; v0.y *= scl; v0.z *= scl; v0.w *= scl;
    v1.x *= scl; v1.y *= scl; v1.z *= scl; v1.w *= scl;
    ss += v0.x * v0.x + v0.y * v0.y + v0.z * v0.z + v0.w * v0.w +
          v1.x * v1.x + v1.y * v1.y + v1.z * v1.z + v1.w * v1.w;
    us8 o;
    o[0] = f2bf(v0.x); o[1] = f2bf(v0.y); o[2] = f2bf(v0.z); o[3] = f2bf(v0.w);
    o[4] = f2bf(v1.x); o[5] = f2bf(v1.y); o[6] = f2bf(v1.z); o[7] = f2bf(v1.w);
    *(us8*)&As[nb][sw_slot(arow, sub) * 8] = o;
  };

  stageB(0, 0);
  stageA(0, 0);
  __syncthreads();

  for (int kb = 0; kb < 8; kb++) {
    int cur = kb & 1, nb = cur ^ 1;
    if (kb < 7) {
      stageB(nb, (kb + 1) * 32);
      stageA(nb, (kb + 1) * 32);
    }
    v8bf af[4], bfv[4];
    int c = lane >> 4;
#pragma unroll
    for (int mi = 0; mi < 4; mi++)
      af[mi] = *(const v8bf*)&As[cur][sw_slot(mi * 16 + (lane & 15), c) * 8];
#pragma unroll
    for (int ni = 0; ni < 4; ni++)
      bfv[ni] = *(const v8bf*)&Bs[cur][sw_slot(w * 64 + ni * 16 + (lane & 15), c) * 8];
#pragma unroll
    for (int mi = 0; mi < 4; mi++)
#pragma unroll
      for (int ni = 0; ni < 4; ni++)
        acc[mi][ni] = __builtin_amdgcn_mfma_f32_16x16x32_bf16(
            af[mi], bfv[ni], acc[mi][ni], 0, 0, 0);
    __syncthreads();
  }

  ss += __shfl_xor(ss, 1, 64);
  ss += __shfl_xor(ss, 2, 64);
  if (sub == 0) sq_s[arow] = ss;
  __syncthreads();

#pragma unroll
  for (int mi = 0; mi < 4; mi++)
#pragma unroll
    for (int ni = 0; ni < 4; ni++) {
      int i = w * 64 + ni * 16 + (lane & 15);  // rf index
      float xrv = xr_s[i], xiv = xi_s[i];
      float c1v = c1_s[i], c2v = c2_s[i], mgv = mg2_s[i];
#pragma unroll
      for (int reg = 0; reg < 4; reg++) {
        int rglob = mi * 16 + (lane >> 4) * 4 + reg;   // row within block
        float px = acc[mi][ni][reg];
        float tt = scaleC * px + bias_s[rglob];
        float u  = 0.5f * sq_s[rglob];
        float aa = u * c1v + mgv;
        float bb = u * c2v;
        float txr = tt * xrv;
        float txi = tt * xiv;
        float erp = __expf(txr - aa);
        float erm = __expf(-txr - aa);
        float s1, cc1, s2, cc2;
        __sincosf(txi - bb, &s1, &cc1);
        __sincosf(txi + bb, &s2, &cc2);
        ushort4 ov;
        ov.x = f2bf(sR * erp * cc1);
        ov.y = f2bf(sR * erm * cc2);
        ov.z = f2bf(sI * erp * s1);
        ov.w = f2bf(-sI * erm * s2);
        *(ushort4*)(Fout + (size_t)(blockRow + rglob) * KDIM + 4 * i) = ov;
      }
    }
}

// ---------------------------------------------------------------------------
// 256x256 8-phase GEMM on mfma_f32_32x32x16_bf16, CHUNK-MAJOR LDS layout.
// R4 post-mortem: row-major LDS + XOR swizzle cannot de-conflict the 32-row
// fragment read (fixed chunk x 32 rows -> bank depends only on 8 granule
// residues -> pigeonhole 4-way). Fix: within each 128-row half, granule
// index = chunk*128 + row  =>  a fragment read (fixed chunk, rows
// base+(lane&31)) hits CONSECUTIVE 16B granules = canonical stride-1
// ds_read_b128 (conflict-free, m134). No XOR anywhere. Staging dests,
// half structure, vmcnt counts (2 loads/half/thread), barrier schedule,
// setprio: identical to the verified skeleton — only the linear-slot ->
// (row,chunk) content mapping and the read addressing changed.
//   A-frag (32x32x16): row = lane&31, k = (lane>>5)*8 + e
//   C/D: col = lane&31, row = (reg&3) + 8*(reg>>2) + 4*(lane>>5)
// ---------------------------------------------------------------------------
#define WAITV(N) asm volatile("s_waitcnt vmcnt(" #N ")" ::: "memory")

__global__ __launch_bounds__(512) void gemm_bt(
    const unsigned short* __restrict__ A,   // NROWS x KDIM bf16
    const unsigned short* __restrict__ B,   // OUTD x KDIM bf16
    float* __restrict__ C) {                // NROWS x OUTD fp32
  __shared__ __align__(16) unsigned short As[2][256 * 64];
  __shared__ __align__(16) unsigned short Bs[2][256 * 64];
  int tt = threadIdx.x;
  int lane = tt & 63;
  int wv = tt >> 6;
  int wm = wv >> 2, wn = wv & 3;           // 2 x 4 wave grid

  // XCD-aware bijective swizzle (1024 % 8 == 0)
  int lid = blockIdx.x;
  int wg = (lid & 7) * 128 + (lid >> 3);
  size_t bm = (size_t)(wg >> 2) * 256;
  size_t bn = (size_t)(wg & 3) * 256;

  // Per-thread staging source offsets (elements). Linear slot L = i*512 + tt
  // within a half holds (chunk = L>>7, row-in-half = L&127).
  // Row permutation (LDS rho -> global row), so each half = one phase's rows:
  //   A: rho = mh*128 + wm*64 + rr   <-> g = wm*128 + mh*64 + rr
  //   B: rho = nh*128 + wn*32 + j    <-> g = wn*64  + nh*32 + j
  unsigned int offA[2][2], offB[2][2];
#pragma unroll
  for (int h = 0; h < 2; h++)
#pragma unroll
    for (int i = 0; i < 2; i++) {
      int L = i * 512 + tt;
      int c = L >> 7;                      // chunk 0..7 (k-offset c*8)
      int r = L & 127;                     // row within half
      int rho = h * 128 + r;
      int gA = ((rho >> 6) & 1) * 128 + (rho >> 7) * 64 + (rho & 63);
      int gB = ((rho >> 5) & 3) * 64 + (rho >> 7) * 32 + (rho & 31);
      offA[h][i] = (unsigned int)((bm + gA) * KDIM + c * 8);
      offB[h][i] = (unsigned int)((bn + gB) * KDIM + c * 8);
    }

#define STAGE_A(H, KB) do { \
  _Pragma("unroll") for (int i_ = 0; i_ < 2; i_++) \
    async_copy16(A + offA[H][i_] + (KB), \
                 &As[nbuf][((H) * 1024 + i_ * 512 + (tt & ~63)) * 8]); \
} while (0)
#define STAGE_B(H, KB) do { \
  _Pragma("unroll") for (int i_ = 0; i_ < 2; i_++) \
    async_copy16(B + offB[H][i_] + (KB), \
                 &Bs[nbuf][((H) * 1024 + i_ * 512 + (tt & ~63)) * 8]); \
} while (0)

  // af[mf_][ks]: A frags for current row-half (mf_ 0..1), ks 0..3
  v8bf af[2][4], b0[4], b1[4];
  f32x16 acc[4][2];
#pragma unroll
  for (int a = 0; a < 4; a++)
#pragma unroll
    for (int b = 0; b < 2; b++)
#pragma unroll
      for (int q = 0; q < 16; q++) acc[a][b][q] = 0.f;

  int hi = lane >> 5;
#define READ_A(MH) do { \
  _Pragma("unroll") for (int mf_ = 0; mf_ < 2; mf_++) { \
    int rl_ = wm * 64 + mf_ * 32 + (lane & 31); \
    const unsigned short* hp_ = &As[buf][((MH) * 1024 + rl_) * 8]; \
    _Pragma("unroll") for (int ks_ = 0; ks_ < 4; ks_++) \
      af[mf_][ks_] = *(const v8bf*)&hp_[((2 * ks_ + hi) * 128) * 8]; \
  } \
} while (0)
#define READ_B(NH, DST) do { \
  { \
    int rl_ = wn * 32 + (lane & 31); \
    const unsigned short* hp_ = &Bs[buf][((NH) * 1024 + rl_) * 8]; \
    _Pragma("unroll") for (int ks_ = 0; ks_ < 4; ks_++) \
      DST[ks_] = *(const v8bf*)&hp_[((2 * ks_ + hi) * 128) * 8]; \
  } \
} while (0)
#define MMA_Q(MH, NH, BSRC) do { \
  __builtin_amdgcn_s_setprio(1); \
  _Pragma("unroll") for (int mf_ = 0; mf_ < 2; mf_++) \
  _Pragma("unroll") for (int ks_ = 0; ks_ < 4; ks_++) \
    acc[(MH) * 2 + mf_][NH] = __builtin_amdgcn_mfma_f32_32x32x16_bf16( \
        af[mf_][ks_], BSRC[ks_], acc[(MH) * 2 + mf_][NH], 0, 0, 0); \
  __builtin_amdgcn_s_setprio(0); \
} while (0)

  // Prologue: stage tile 0 fully into buf 0 (order Ah0, Bh0, Bh1, Ah1).
  {
    const int nbuf = 0;
    STAGE_A(0, 0); STAGE_B(0, 0); STAGE_B(1, 0); STAGE_A(1, 0);
  }
  WAITV(4);                         // Ah0 + Bh0 landed (own wave)
  __builtin_amdgcn_s_barrier();     // -> landed for all waves

  for (int t = 0; t < 16; ++t) {
    const int buf = t & 1, nbuf = buf ^ 1;
    const bool pf = (t < 15);
    const int kb = (t + 1) * 64;

    // ---- Phase 1: read Ah0 + Bh0 frags, stage Ah0(next), MFMA Q(0,0)
    READ_A(0); READ_B(0, b0);
    if (pf) STAGE_A(0, kb);
    __builtin_amdgcn_s_barrier();
    MMA_Q(0, 0, b0);
    if (pf) { WAITV(4); } else { WAITV(2); }   // next: Bh1 of current tile
    __builtin_amdgcn_s_barrier();

    // ---- Phase 2: read Bh1 frags, stage Bh0(next), MFMA Q(0,1)
    READ_B(1, b1);
    if (pf) STAGE_B(0, kb);
    __builtin_amdgcn_s_barrier();
    MMA_Q(0, 1, b1);
    if (pf) { WAITV(4); } else { WAITV(0); }   // next: Ah1 of current tile
    __builtin_amdgcn_s_barrier();

    // ---- Phase 3: read Ah1 frags, stage Bh1(next), MFMA Q(1,1)
    READ_A(1);
    if (pf) STAGE_B(1, kb);
    __builtin_amdgcn_s_barrier();
    MMA_Q(1, 1, b1);
    __builtin_amdgcn_s_barrier();              // P4 reads nothing: no wait

    // ---- Phase 4: stage Ah1(next), MFMA Q(1,0) (b0 still live)
    if (pf) STAGE_A(1, kb);
    __builtin_amdgcn_s_barrier();
    MMA_Q(1, 0, b0);
    if (pf) { WAITV(4); }                      // next tile P1: Ah0+Bh0 landed
    __builtin_amdgcn_s_barrier();
  }

  // C-write: 32 lanes x 4 B contiguous = 128-B segments per store instr.
#pragma unroll
  for (int fa = 0; fa < 4; fa++)
#pragma unroll
    for (int nf = 0; nf < 2; nf++)
#pragma unroll
      for (int reg = 0; reg < 16; reg++) {
        size_t row = bm + wm * 128 + fa * 32 +
                     (reg & 3) + 8 * (reg >> 2) + 4 * (lane >> 5);
        size_t col = bn + wn * 64 + nf * 32 + (lane & 31);
        C[row * OUTD + col] = acc[fa][nf][reg];
      }
#undef STAGE_A
#undef STAGE_B
#undef READ_A
#undef READ_B
#undef MMA_Q
}

extern "C" void kernel_launch(void* const* d_in, const int* in_sizes, int n_in,
                              void* d_out, int out_size, void* d_ws, size_t ws_size,
                              hipStream_t stream) {
  (void)in_sizes; (void)n_in; (void)out_size;
  const float* x    = (const float*)d_in[0];
  const float* iw   = (const float*)d_in[1];
  const float* bvec = (const float*)d_in[2];
  const float* proj = (const float*)d_in[3];
  const float* xr   = (const float*)d_in[4];
  const float* xi   = (const float*)d_in[5];
  float* out = (float*)d_out;

  char* ws = (char*)d_ws;
  size_t off = 0;
  auto take = [&](size_t bytes) {
    char* p = ws + off;
    off = (off + bytes + 255) & ~(size_t)255;
    return p;
  };
  unsigned short* F      = (unsigned short*)take((size_t)NROWS * KDIM * 2);  // 134 MB
  unsigned short* Wp     = (unsigned short*)take((size_t)OUTD * KDIM * 2);   // 2 MB
  unsigned short* projbf = (unsigned short*)take((size_t)NRF * DIMN * 2);    // 128 KB
  float* mg2 = (float*)take((size_t)NRF * 4);
  if (ws_size < off) return;

  const float  scaleC = sqrtf(1.f + 4.f * MCOEF);
  const double c2d    = 0.5 * exp(128.0 * log(1.0 + 4.0 * 0.001));
  const float  invSR  = 0.0625f;
  const float  sRw    = (float)(c2d * 0.0625);

  prep_rf<<<NRF, 64, 0, stream>>>(proj, projbf, mg2);
  fused_features<<<NROWS / 64 + OUTD / 64, 256, 0, stream>>>(
      x, iw, bvec, xr, xi, mg2, projbf, F, Wp, invSR, sRw, scaleC);
  gemm_bt<<<1024, 512, 0, stream>>>(F, Wp, out);
}

// Round 6
// 496.445 us; speedup vs baseline: 1.0137x; 1.0137x over previous
//
#include <hip/hip_runtime.h>
#include <cmath>
#include <cstdint>

#define NROWS 65536
#define DIMN  256
#define NRF   256
#define OUTD  1024
#define KDIM  1024   // 4*NRF
#define MCOEF 0.001f

typedef __bf16 v8bf __attribute__((ext_vector_type(8)));
typedef float  v4f  __attribute__((ext_vector_type(4)));
typedef unsigned short us8 __attribute__((ext_vector_type(8)));

__device__ __forceinline__ unsigned short f2bf(float f) {
  unsigned int u = __float_as_uint(f);
  u += 0x7fffu + ((u >> 16) & 1u);   // round-to-nearest-even
  return (unsigned short)(u >> 16);
}

__device__ __forceinline__ void async_copy16(const void* g, void* l) {
  __builtin_amdgcn_global_load_lds(
      (const __attribute__((address_space(1))) void*)g,
      (__attribute__((address_space(3))) void*)l, 16, 0, 0);
}

// XOR-swizzled tile layout (16-row fragment reads: conflict-free, measured R3).
__device__ __forceinline__ int sw_slot(int r, int c) {
  return r * 4 + ((c ^ (r >> 1)) & 3);
}

// proj -> bf16, and mg2[i] = M * ||proj_i||^2 (fp32)
__global__ __launch_bounds__(64) void prep_rf(
    const float* __restrict__ proj, unsigned short* __restrict__ projbf,
    float* __restrict__ mg2) {
  int i = blockIdx.x;
  int lane = threadIdx.x;  // 64 threads
  float4 v = ((const float4*)(proj + (size_t)i * DIMN))[lane];
  ushort4 o;
  o.x = f2bf(v.x); o.y = f2bf(v.y); o.z = f2bf(v.z); o.w = f2bf(v.w);
  ((ushort4*)(projbf + (size_t)i * DIMN))[lane] = o;
  float ss = v.x * v.x + v.y * v.y + v.z * v.z + v.w * v.w;
#pragma unroll
  for (int off = 32; off > 0; off >>= 1) ss += __shfl_down(ss, off, 64);
  if (lane == 0) mg2[i] = MCOEF * ss;
}

// Fused feature kernel for BOTH x (blocks 16..1039) and weights (blocks 0..15).
// K layout INTERLEAVED: column k = 4*rf + component (identical F and Wp).
// v4: software-pipelined A-path. Per iter: issue x-loads(k+1) + B-prefetch(k+1)
// FIRST, then ds_read+MFMA of k (loads fly under compute), THEN convert/
// ds_write the k+1 A-tile (x-loads landed by now), then barrier (all
// outstanding vmem is old -> drain ~free). Previously the x-loads were
// consumed immediately after issue -> ~900 cyc HBM latency exposed per iter.
__global__ __launch_bounds__(256) void fused_features(
    const float* __restrict__ srcX,          // 65536 x 256 fp32
    const float* __restrict__ srcW,          // 1024 x 256 fp32
    const float* __restrict__ biasW,         // raw b (scaled by 0.25 here)
    const float* __restrict__ xr_g, const float* __restrict__ xi_g,
    const float* __restrict__ mg2_g,
    const unsigned short* __restrict__ projbf,  // 256 x 256 bf16
    unsigned short* __restrict__ FX,         // 65536 x 1024 bf16
    unsigned short* __restrict__ FW,         // 1024 x 1024 bf16
    float sRx, float sRw, float scaleC) {
  __shared__ __align__(16) unsigned short As[2][64 * 32];    // 2 x 4 KB
  __shared__ __align__(16) unsigned short Bs[2][256 * 32];   // 2 x 16 KB
  __shared__ float xr_s[256], xi_s[256], c1_s[256], c2_s[256], mg2_s[256];
  __shared__ float sq_s[64], bias_s[64];

  int t = threadIdx.x;
  int lane = t & 63;
  int w = t >> 6;

  bool isW = blockIdx.x < (OUTD / 64);
  int blockRow = isW ? blockIdx.x * 64 : (blockIdx.x - OUTD / 64) * 64;
  const float* src = isW ? srcW : srcX;
  float scl = isW ? 0.25f : (1.f / DIMN);
  unsigned short* Fout = isW ? FW : FX;
  float sR = isW ? sRw : sRx;
  float sI = isW ? -sRw : sRx;

  {
    float a = xr_g[t], b = xi_g[t];
    xr_s[t] = a; xi_s[t] = b;
    c1_s[t] = a * a - b * b;   // Re(z^2)
    c2_s[t] = 2.f * a * b;     // Im(z^2)
    mg2_s[t] = mg2_g[t];
  }
  if (t < 64) bias_s[t] = isW ? biasW[blockRow + t] * 0.25f : 0.f;

  v4f acc[4][4];
#pragma unroll
  for (int a = 0; a < 4; a++)
#pragma unroll
    for (int b = 0; b < 4; b++)
#pragma unroll
      for (int q = 0; q < 4; q++) acc[a][b][q] = 0.f;

  int arow = t >> 2, sub = t & 3;
  const float* srow = src + (size_t)(blockRow + arow) * DIMN + sub * 8;
  float ss = 0.f;

  auto stageB = [&](int nb, int kb) {
#pragma unroll
    for (int r = 0; r < 4; r++) {
      int idx = r * 256 + t;
      int row = idx >> 2, kc = ((idx & 3) ^ ((idx >> 3) & 3)) * 8;
      async_copy16(projbf + (size_t)row * DIMN + kb + kc,
                   &Bs[nb][(idx & ~63) * 8]);
    }
  };
  // convert + write one A tile from already-loaded registers
  auto cvtA = [&](int nb, float4 v0, float4 v1) {
    v0.x *= scl; v0.y *= scl; v0.z *= scl; v0.w *= scl;
    v1.x *= scl; v1.y *= scl; v1.z *= scl; v1.w *= scl;
    ss += v0.x * v0.x + v0.y * v0.y + v0.z * v0.z + v0.w * v0.w +
          v1.x * v1.x + v1.y * v1.y + v1.z * v1.z + v1.w * v1.w;
    us8 o;
    o[0] = f2bf(v0.x); o[1] = f2bf(v0.y); o[2] = f2bf(v0.z); o[3] = f2bf(v0.w);
    o[4] = f2bf(v1.x); o[5] = f2bf(v1.y); o[6] = f2bf(v1.z); o[7] = f2bf(v1.w);
    *(us8*)&As[nb][sw_slot(arow, sub) * 8] = o;
  };

  // Prologue: tile 0 (B async; A via registers)
  stageB(0, 0);
  {
    float4 p0 = *(const float4*)(srow);
    float4 p1 = *(const float4*)(srow + 4);
    cvtA(0, p0, p1);
  }
  __syncthreads();

  for (int kb = 0; kb < 8; kb++) {
    int cur = kb & 1, nb = cur ^ 1;
    float4 n0, n1;
    if (kb < 7) {
      // issue next-tile loads FIRST; consumed only after the MFMA phase
      n0 = *(const float4*)(srow + (kb + 1) * 32);
      n1 = *(const float4*)(srow + (kb + 1) * 32 + 4);
      stageB(nb, (kb + 1) * 32);
    }
    v8bf af[4], bfv[4];
    int c = lane >> 4;
#pragma unroll
    for (int mi = 0; mi < 4; mi++)
      af[mi] = *(const v8bf*)&As[cur][sw_slot(mi * 16 + (lane & 15), c) * 8];
#pragma unroll
    for (int ni = 0; ni < 4; ni++)
      bfv[ni] = *(const v8bf*)&Bs[cur][sw_slot(w * 64 + ni * 16 + (lane & 15), c) * 8];
#pragma unroll
    for (int mi = 0; mi < 4; mi++)
#pragma unroll
      for (int ni = 0; ni < 4; ni++)
        acc[mi][ni] = __builtin_amdgcn_mfma_f32_16x16x32_bf16(
            af[mi], bfv[ni], acc[mi][ni], 0, 0, 0);
    if (kb < 7) cvtA(nb, n0, n1);   // x-loads landed under MFMA
    __syncthreads();                // B-prefetch is old by now -> cheap drain
  }

  ss += __shfl_xor(ss, 1, 64);
  ss += __shfl_xor(ss, 2, 64);
  if (sub == 0) sq_s[arow] = ss;
  __syncthreads();

#pragma unroll
  for (int mi = 0; mi < 4; mi++)
#pragma unroll
    for (int ni = 0; ni < 4; ni++) {
      int i = w * 64 + ni * 16 + (lane & 15);  // rf index
      float xrv = xr_s[i], xiv = xi_s[i];
      float c1v = c1_s[i], c2v = c2_s[i], mgv = mg2_s[i];
#pragma unroll
      for (int reg = 0; reg < 4; reg++) {
        int rglob = mi * 16 + (lane >> 4) * 4 + reg;   // row within block
        float px = acc[mi][ni][reg];
        float tt = scaleC * px + bias_s[rglob];
        float u  = 0.5f * sq_s[rglob];
        float aa = u * c1v + mgv;
        float bb = u * c2v;
        float txr = tt * xrv;
        float txi = tt * xiv;
        float erp = __expf(txr - aa);
        float erm = __expf(-txr - aa);
        float s1, cc1, s2, cc2;
        __sincosf(txi - bb, &s1, &cc1);
        __sincosf(txi + bb, &s2, &cc2);
        ushort4 ov;
        ov.x = f2bf(sR * erp * cc1);
        ov.y = f2bf(sR * erm * cc2);
        ov.z = f2bf(sI * erp * s1);
        ov.w = f2bf(-sI * erm * s2);
        *(ushort4*)(Fout + (size_t)(blockRow + rglob) * KDIM + 4 * i) = ov;
      }
    }
}

// ---------------------------------------------------------------------------
// 256x256 8-phase GEMM — REVERTED to the R3-verified 16x16 version (181 us,
// 0 bank conflicts, coalesced staging). Both 32x32 variants are dominated:
// row-major XOR conflicts on 32-row fragment reads (R4, 12.6M conflicts);
// chunk-major de-conflicts LDS but scatters the global_load_lds source
// 64-way (R5, vmem-issue bound). 16x16 satisfies both sides.
// ---------------------------------------------------------------------------
#define WAITV(N) asm volatile("s_waitcnt vmcnt(" #N ")" ::: "memory")

__global__ __launch_bounds__(512) void gemm_bt(
    const unsigned short* __restrict__ A,   // NROWS x KDIM bf16
    const unsigned short* __restrict__ B,   // OUTD x KDIM bf16
    float* __restrict__ C) {                // NROWS x OUTD fp32
  __shared__ __align__(16) unsigned short As[2][256 * 64];
  __shared__ __align__(16) unsigned short Bs[2][256 * 64];
  int tt = threadIdx.x;
  int lane = tt & 63;
  int wv = tt >> 6;
  int wm = wv >> 2, wn = wv & 3;           // 2 x 4 wave grid

  // XCD-aware bijective swizzle (1024 % 8 == 0)
  int lid = blockIdx.x;
  int wg = (lid & 7) * 128 + (lid >> 3);
  size_t bm = (size_t)(wg >> 2) * 256;
  size_t bn = (size_t)(wg & 3) * 256;

  // Per-thread staging source offsets (elements). L = i*512 + tt within a half.
  unsigned int offA[2][2], offB[2][2];
#pragma unroll
  for (int h = 0; h < 2; h++)
#pragma unroll
    for (int i = 0; i < 2; i++) {
      int L = i * 512 + tt;
      int rho = h * 128 + (L >> 3);
      int c = (L & 7) ^ (rho & 7);         // pre-swizzled global chunk
      int gA = ((rho >> 6) & 1) * 128 + (rho >> 7) * 64 + (rho & 63);
      int gB = ((rho >> 5) & 3) * 64 + (rho >> 7) * 32 + (rho & 31);
      offA[h][i] = (unsigned int)((bm + gA) * KDIM + c * 8);
      offB[h][i] = (unsigned int)((bn + gB) * KDIM + c * 8);
    }

#define STAGE_A(H, KB) do { \
  _Pragma("unroll") for (int i_ = 0; i_ < 2; i_++) \
    async_copy16(A + offA[H][i_] + (KB), \
                 &As[nbuf][((H) * 1024 + i_ * 512 + (tt & ~63)) * 8]); \
} while (0)
#define STAGE_B(H, KB) do { \
  _Pragma("unroll") for (int i_ = 0; i_ < 2; i_++) \
    async_copy16(B + offB[H][i_] + (KB), \
                 &Bs[nbuf][((H) * 1024 + i_ * 512 + (tt & ~63)) * 8]); \
} while (0)

  v8bf af[4][2], b0[2][2], b1[2][2];
  v4f acc[8][4];
#pragma unroll
  for (int a = 0; a < 8; a++)
#pragma unroll
    for (int b = 0; b < 4; b++)
#pragma unroll
      for (int q = 0; q < 4; q++) acc[a][b][q] = 0.f;

#define READ_A(MH) do { \
  _Pragma("unroll") for (int mf_ = 0; mf_ < 4; mf_++) { \
    int rho_ = (MH) * 128 + wm * 64 + mf_ * 16 + (lane & 15); \
    int sw_ = rho_ & 7; \
    const unsigned short* rp_ = &As[buf][rho_ * 64]; \
    af[mf_][0] = *(const v8bf*)&rp_[(((lane >> 4)) ^ sw_) * 8]; \
    af[mf_][1] = *(const v8bf*)&rp_[((4 + (lane >> 4)) ^ sw_) * 8]; \
  } \
} while (0)
#define READ_B(NH, DST) do { \
  _Pragma("unroll") for (int nf_ = 0; nf_ < 2; nf_++) { \
    int rho_ = (NH) * 128 + wn * 32 + nf_ * 16 + (lane & 15); \
    int sw_ = rho_ & 7; \
    const unsigned short* rp_ = &Bs[buf][rho_ * 64]; \
    DST[nf_][0] = *(const v8bf*)&rp_[(((lane >> 4)) ^ sw_) * 8]; \
    DST[nf_][1] = *(const v8bf*)&rp_[((4 + (lane >> 4)) ^ sw_) * 8]; \
  } \
} while (0)
#define MMA_Q(MH, NH, BSRC) do { \
  __builtin_amdgcn_s_setprio(1); \
  _Pragma("unroll") for (int mf_ = 0; mf_ < 4; mf_++) \
  _Pragma("unroll") for (int nf_ = 0; nf_ < 2; nf_++) \
  _Pragma("unroll") for (int ks_ = 0; ks_ < 2; ks_++) \
    acc[(MH) * 4 + mf_][(NH) * 2 + nf_] = \
        __builtin_amdgcn_mfma_f32_16x16x32_bf16( \
            af[mf_][ks_], BSRC[nf_][ks_], \
            acc[(MH) * 4 + mf_][(NH) * 2 + nf_], 0, 0, 0); \
  __builtin_amdgcn_s_setprio(0); \
} while (0)

  // Prologue: stage tile 0 fully into buf 0 (order Ah0, Bh0, Bh1, Ah1).
  {
    const int nbuf = 0;
    STAGE_A(0, 0); STAGE_B(0, 0); STAGE_B(1, 0); STAGE_A(1, 0);
  }
  WAITV(4);                         // Ah0 + Bh0 landed (own wave)
  __builtin_amdgcn_s_barrier();     // -> landed for all waves

  for (int t = 0; t < 16; ++t) {
    const int buf = t & 1, nbuf = buf ^ 1;
    const bool pf = (t < 15);
    const int kb = (t + 1) * 64;

    // ---- Phase 1: read Ah0 + Bh0 frags, stage Ah0(next), MFMA Q(0,0)
    READ_A(0); READ_B(0, b0);
    if (pf) STAGE_A(0, kb);
    __builtin_amdgcn_s_barrier();
    MMA_Q(0, 0, b0);
    if (pf) { WAITV(4); } else { WAITV(2); }   // next: Bh1 of current tile
    __builtin_amdgcn_s_barrier();

    // ---- Phase 2: read Bh1 frags, stage Bh0(next), MFMA Q(0,1)
    READ_B(1, b1);
    if (pf) STAGE_B(0, kb);
    __builtin_amdgcn_s_barrier();
    MMA_Q(0, 1, b1);
    if (pf) { WAITV(4); } else { WAITV(0); }   // next: Ah1 of current tile
    __builtin_amdgcn_s_barrier();

    // ---- Phase 3: read Ah1 frags, stage Bh1(next), MFMA Q(1,1)
    READ_A(1);
    if (pf) STAGE_B(1, kb);
    __builtin_amdgcn_s_barrier();
    MMA_Q(1, 1, b1);
    __builtin_amdgcn_s_barrier();              // P4 reads nothing: no wait

    // ---- Phase 4: stage Ah1(next), MFMA Q(1,0) (b0 still live)
    if (pf) STAGE_A(1, kb);
    __builtin_amdgcn_s_barrier();
    MMA_Q(1, 0, b0);
    if (pf) { WAITV(4); }                      // next tile P1: Ah0+Bh0 landed
    __builtin_amdgcn_s_barrier();
  }

#pragma unroll
  for (int mf = 0; mf < 8; mf++)
#pragma unroll
    for (int nf = 0; nf < 4; nf++)
#pragma unroll
      for (int reg = 0; reg < 4; reg++) {
        size_t row = bm + wm * 128 + mf * 16 + (lane >> 4) * 4 + reg;
        size_t col = bn + wn * 64 + nf * 16 + (lane & 15);
        C[row * OUTD + col] = acc[mf][nf][reg];
      }
#undef STAGE_A
#undef STAGE_B
#undef READ_A
#undef READ_B
#undef MMA_Q
}

extern "C" void kernel_launch(void* const* d_in, const int* in_sizes, int n_in,
                              void* d_out, int out_size, void* d_ws, size_t ws_size,
                              hipStream_t stream) {
  (void)in_sizes; (void)n_in; (void)out_size;
  const float* x    = (const float*)d_in[0];
  const float* iw   = (const float*)d_in[1];
  const float* bvec = (const float*)d_in[2];
  const float* proj = (const float*)d_in[3];
  const float* xr   = (const float*)d_in[4];
  const float* xi   = (const float*)d_in[5];
  float* out = (float*)d_out;

  char* ws = (char*)d_ws;
  size_t off = 0;
  auto take = [&](size_t bytes) {
    char* p = ws + off;
    off = (off + bytes + 255) & ~(size_t)255;
    return p;
  };
  unsigned short* F      = (unsigned short*)take((size_t)NROWS * KDIM * 2);  // 134 MB
  unsigned short* Wp     = (unsigned short*)take((size_t)OUTD * KDIM * 2);   // 2 MB
  unsigned short* projbf = (unsigned short*)take((size_t)NRF * DIMN * 2);    // 128 KB
  float* mg2 = (float*)take((size_t)NRF * 4);
  if (ws_size < off) return;

  const float  scaleC = sqrtf(1.f + 4.f * MCOEF);
  const double c2d    = 0.5 * exp(128.0 * log(1.0 + 4.0 * 0.001));
  const float  invSR  = 0.0625f;
  const float  sRw    = (float)(c2d * 0.0625);

  prep_rf<<<NRF, 64, 0, stream>>>(proj, projbf, mg2);
  fused_features<<<NROWS / 64 + OUTD / 64, 256, 0, stream>>>(
      x, iw, bvec, xr, xi, mg2, projbf, F, Wp, invSR, sRw, scaleC);
  gemm_bt<<<1024, 512, 0, stream>>>(F, Wp, out);
}